// Round 17
// baseline (787.259 us; speedup 1.0000x reference)
//
#include <hip/hip_runtime.h>
#include <math.h>

#define N_ 16
#define C_ 4
#define F_ 257
#define T_ 1000
#define B_ 8
#define K_ 80
#define BK_ 640
#define TT_ 16
#define NT_ 63            // ceil(1000/16)
#define NBLK (N_ * NT_)   // 1008

typedef _Float16 half4 __attribute__((ext_vector_type(4)));
typedef _Float16 half8 __attribute__((ext_vector_type(8)));
typedef float f32x4 __attribute__((ext_vector_type(4)));

#define WSCALE   256.0f          // dodge f16 subnormals in w0
#define WUNSCALE 0.00390625f     // 2^-8

// d_ws byte offsets
#define WP0_OFF   0               // 80 frags * 64 lanes * 4 halves = 40960 B
#define WP1_OFF   (64 * 1024)
#define WP2_OFF   (128 * 1024)
#define WTAIL_OFF (192 * 1024)    // 80 f32
#define PART_OFF  (256 * 1024)    // NBLK*16 doubles
#define SS_OFF    (PART_OFF + NBLK * 16 * 8)

// ---- pack w_proj into 16x16x16 B-fragment layout, 3-term f16 split --------
// frag blk = ch*10 + kt*2 + ksub. lane L, elem j:
//   B[f = ch*32 + ksub*16 + 4*(L/16) + j][k = kt*16 + L%16], scaled by 256.
__global__ __launch_bounds__(80) void k_wt(const float* __restrict__ wp,
                                           _Float16* __restrict__ wp0,
                                           _Float16* __restrict__ wp1,
                                           _Float16* __restrict__ wp2,
                                           float* __restrict__ wtail) {
    int blk = blockIdx.x;
    int tid = threadIdx.x;
    if (blk < 80) {
        if (tid < 64) {
            int ch = blk / 10, r = blk % 10, kt = r >> 1, ksub = r & 1;
            int k = kt * 16 + (tid & 15);
            int fb = ch * 32 + ksub * 16 + 4 * (tid >> 4);
#pragma unroll
            for (int j = 0; j < 4; ++j) {
                float w = wp[k * F_ + fb + j] * WSCALE;
                _Float16 w0 = (_Float16)w;
                float r1 = (w - (float)w0) * 2048.0f;
                _Float16 w1 = (_Float16)r1;
                float r2 = (r1 - (float)w1) * 2048.0f;
                _Float16 w2 = (_Float16)r2;
                size_t o = ((size_t)blk * 64 + tid) * 4 + j;
                wp0[o] = w0; wp1[o] = w1; wp2[o] = w2;
            }
        }
    } else {
        wtail[tid] = wp[tid * F_ + 256];   // f = 256 column, f32 (no scaling)
    }
}

// Fused beamform (pre-split f16 A-frags, conflict-free) + 3-term f16 MFMA GEMM
// + relu+log + BN sums.  512 threads = 8 waves; wave = beam b.
// SINGLE-buffered LDS (41 KB) + VGPR<=85 -> 3 blocks/CU (24 waves).
__global__ __launch_bounds__(512, 6) void k_fused(
    const float* __restrict__ xr, const float* __restrict__ xi,
    const float* __restrict__ wr, const float* __restrict__ wi,
    const _Float16* __restrict__ wp0, const _Float16* __restrict__ wp1,
    const _Float16* __restrict__ wp2, const float* __restrict__ wtail,
    float* __restrict__ out, double* __restrict__ partials) {

    const int tid = threadIdx.x;
    const int bid = blockIdx.x;
    const int tt = bid % NT_;
    const int n  = bid / NT_;
    const int t0 = tt * TT_;

    // A-fragments, pre-split: [b][ks][term][lane*4+j]  -> 24.6 KB
    __shared__ __attribute__((aligned(16))) _Float16 aS[B_][2][3][256];
    // B-fragments: [term][frag*256 + lane*4+j]         -> 15.4 KB
    __shared__ __attribute__((aligned(16))) _Float16 wfS[3][2560];
    __shared__ float wtS[80];
    __shared__ float magT[TT_][B_];

    const int lane = tid & 63;
    const int wv   = tid >> 6;                // wave id == beam b

    const int sfr = tid >> 4;                 // staging f-row 0..31
    const int t_s = tid & 15;                 // staging t 0..15
    const int tg  = t0 + t_s;
    const bool tld = (tg < T_);
    // A-frag slot for this staging thread's (f,t):
    const int a_ks = sfr >> 4;                // k-subtile (f div 16)
    const int a_g  = (sfr & 15) >> 2;         // f-quad within subtile
    const int a_j  = sfr & 3;                 // elem within quad
    const int a_off = a_g * 64 + t_s * 4 + a_j;

    f32x4 accM[5], acc1[5], acc2[5];
#pragma unroll
    for (int kt = 0; kt < 5; ++kt) {
        accM[kt] = (f32x4)0.0f;
        acc1[kt] = (f32x4)0.0f;
        acc2[kt] = (f32x4)0.0f;
    }

    const float* xrn = xr + (size_t)n * C_ * F_ * T_;
    const float* xin = xi + (size_t)n * C_ * F_ * T_;

    if (tid < 80) wtS[tid] = wtail[tid];

    // -------- prefetch x for chunk 0 (f = sfr) --------
    float pxr[C_], pxi[C_];
    if (tld) {
#pragma unroll
        for (int c = 0; c < C_; ++c) {
            pxr[c] = xrn[((size_t)c * F_ + sfr) * T_ + tg];
            pxi[c] = xin[((size_t)c * F_ + sfr) * T_ + tg];
        }
    }

    for (int ch = 0; ch < 8; ++ch) {
        const int f0 = ch * 32;
        const int f  = f0 + sfr;

        if (ch > 0) __syncthreads();   // all waves done with GEMM(ch-1)

        // ---- stage w fragments: 3 terms x 2560 halves = 960 x 16B ----
#pragma unroll
        for (int r = 0; r < 2; ++r) {
            int idx = tid + r * 512;
            if (idx < 960) {
                int term = idx / 320;
                int u = idx - term * 320;
                const _Float16* src =
                    (term == 0 ? wp0 : (term == 1 ? wp1 : wp2)) + ch * 2560 + u * 8;
                *(half8*)&wfS[term][u * 8] = *(const half8*)src;
            }
        }

        // ---- beamform mag, 3-term split, write A-frags (2-way banks) ----
        {
#pragma unroll
            for (int b = 0; b < B_; ++b) {
                float v = 0.f;
                if (tld) {
                    const float* wrp = wr + ((size_t)f * B_ + b) * C_;
                    const float* wip = wi + ((size_t)f * B_ + b) * C_;
                    float4 wrv = *(const float4*)wrp;
                    float4 wiv = *(const float4*)wip;
                    float br  = pxr[0] * wrv.x + pxr[1] * wrv.y + pxr[2] * wrv.z + pxr[3] * wrv.w
                              - pxi[0] * wiv.x - pxi[1] * wiv.y - pxi[2] * wiv.z - pxi[3] * wiv.w;
                    float bi2 = pxi[0] * wrv.x + pxi[1] * wrv.y + pxi[2] * wrv.z + pxi[3] * wrv.w
                              + pxr[0] * wiv.x + pxr[1] * wiv.y + pxr[2] * wiv.z + pxr[3] * wiv.w;
                    v = sqrtf(br * br + bi2 * bi2 + 1e-5f);
                }
                _Float16 h0 = (_Float16)v;
                float r1 = (v - (float)h0) * 2048.0f;
                _Float16 h1 = (_Float16)r1;
                float r2 = (r1 - (float)h1) * 2048.0f;
                aS[b][a_ks][0][a_off] = h0;
                aS[b][a_ks][1][a_off] = h1;
                aS[b][a_ks][2][a_off] = (_Float16)r2;
            }
        }

        // ---- prefetch x for ch+1 (in flight across barrier + GEMM) ----
        if (ch < 7 && tld) {
            const int f2 = f0 + 32 + sfr;
#pragma unroll
            for (int c = 0; c < C_; ++c) {
                pxr[c] = xrn[((size_t)c * F_ + f2) * T_ + tg];
                pxi[c] = xin[((size_t)c * F_ + f2) * T_ + tg];
            }
        }

        __syncthreads();

        // ---- MFMA GEMM: A b64 conflict-free, kt-innermost (dep dist 5) ----
#pragma unroll
        for (int ks = 0; ks < 2; ++ks) {
            half4 a0 = *(const half4*)&aS[wv][ks][0][lane * 4];
            half4 a1 = *(const half4*)&aS[wv][ks][1][lane * 4];
            half4 a2 = *(const half4*)&aS[wv][ks][2][lane * 4];
#pragma unroll
            for (int kt = 0; kt < 5; ++kt) {
                half4 b0 = *(const half4*)&wfS[0][((kt * 2 + ks) * 64 + lane) * 4];
                accM[kt] = __builtin_amdgcn_mfma_f32_16x16x16f16(a0, b0, accM[kt], 0, 0, 0);
            }
#pragma unroll
            for (int kt = 0; kt < 5; ++kt) {
                half4 b1 = *(const half4*)&wfS[1][((kt * 2 + ks) * 64 + lane) * 4];
                acc1[kt] = __builtin_amdgcn_mfma_f32_16x16x16f16(a0, b1, acc1[kt], 0, 0, 0);
            }
#pragma unroll
            for (int kt = 0; kt < 5; ++kt) {
                half4 b0 = *(const half4*)&wfS[0][((kt * 2 + ks) * 64 + lane) * 4];
                acc1[kt] = __builtin_amdgcn_mfma_f32_16x16x16f16(a1, b0, acc1[kt], 0, 0, 0);
            }
#pragma unroll
            for (int kt = 0; kt < 5; ++kt) {
                half4 b2 = *(const half4*)&wfS[2][((kt * 2 + ks) * 64 + lane) * 4];
                acc2[kt] = __builtin_amdgcn_mfma_f32_16x16x16f16(a0, b2, acc2[kt], 0, 0, 0);
            }
#pragma unroll
            for (int kt = 0; kt < 5; ++kt) {
                half4 b1 = *(const half4*)&wfS[1][((kt * 2 + ks) * 64 + lane) * 4];
                acc2[kt] = __builtin_amdgcn_mfma_f32_16x16x16f16(a1, b1, acc2[kt], 0, 0, 0);
            }
#pragma unroll
            for (int kt = 0; kt < 5; ++kt) {
                half4 b0 = *(const half4*)&wfS[0][((kt * 2 + ks) * 64 + lane) * 4];
                acc2[kt] = __builtin_amdgcn_mfma_f32_16x16x16f16(a2, b0, acc2[kt], 0, 0, 0);
            }
        }
    }

    // ---- tail f = 256: f32 mag into magT ----
    if (tid < 128) {
        int trow = tid >> 3;
        int b = tid & 7;
        int t = t0 + trow;
        float v = 0.f;
        if (t < T_) {
            const float* wrp = wr + (size_t)(256 * B_ + b) * C_;
            const float* wip = wi + (size_t)(256 * B_ + b) * C_;
            float br = 0.f, bi2 = 0.f;
#pragma unroll
            for (int c = 0; c < C_; ++c) {
                float xrv = xrn[((size_t)c * F_ + 256) * T_ + t];
                float xiv = xin[((size_t)c * F_ + 256) * T_ + t];
                br  += xrv * wrp[c] - xiv * wip[c];
                bi2 += xiv * wrp[c] + xrv * wip[c];
            }
            v = sqrtf(br * br + bi2 * bi2 + 1e-5f);
        }
        magT[trow][b] = v;
    }
    __syncthreads();

    // ---- epilogue: combine 3-term accs (unscale) + tail, relu+log, BN ----
    const int col = lane & 15;
    const int g   = lane >> 4;
    float s1 = 0.f, s2 = 0.f;
#pragma unroll
    for (int kt = 0; kt < 5; ++kt) {
        f32x4 r = (accM[kt] + 4.8828125e-4f * acc1[kt]
                   + 2.384185791015625e-7f * acc2[kt]) * WUNSCALE;
#pragma unroll
        for (int reg = 0; reg < 4; ++reg) {
            int trow = 4 * g + reg;
            int t = t0 + trow;
            float sum = r[reg] + magT[trow][wv] * wtS[kt * 16 + col];
            if (t < T_) {
                float v = fmaxf(sum, 0.0f);
                v = __logf(v + 1e-5f);
                out[((size_t)n * T_ + t) * BK_ + wv * K_ + kt * 16 + col] = v;
                s1 += v;
                s2 += v * v;
            }
        }
    }
    double d1 = (double)s1, d2 = (double)s2;
#pragma unroll
    for (int off = 32; off; off >>= 1) {
        d1 += __shfl_xor(d1, off);
        d2 += __shfl_xor(d2, off);
    }
    if (lane == 0) {
        partials[(size_t)bid * 16 + wv] = d1;
        partials[(size_t)bid * 16 + 8 + wv] = d2;
    }
}

// ---------------- reduce partials -> per-channel scale/shift ----------------
__global__ __launch_bounds__(256) void k_bnstats(
    const double* __restrict__ partials,
    const float* __restrict__ gamma, const float* __restrict__ beta,
    float* __restrict__ ss) {
    const int b = threadIdx.x >> 5;
    const int i = threadIdx.x & 31;
    double s1 = 0.0, s2 = 0.0;
    for (int j = i; j < NBLK; j += 32) {
        s1 += partials[(size_t)j * 16 + b];
        s2 += partials[(size_t)j * 16 + 8 + b];
    }
#pragma unroll
    for (int off = 16; off; off >>= 1) {
        s1 += __shfl_down(s1, off);
        s2 += __shfl_down(s2, off);
    }
    if (i == 0) {
        const double cnt = (double)N_ * T_ * K_;
        double mean = s1 / cnt;
        double var = s2 / cnt - mean * mean;
        float scale = gamma[b] * (float)(1.0 / sqrt(var + 1e-5));
        float shift = beta[b] - (float)mean * scale;
        ss[b] = scale;
        ss[B_ + b] = shift;
    }
}

// ---------------- apply BN in place over d_out ----------------
__global__ __launch_bounds__(256) void k_bnapply(float* __restrict__ out,
                                                 const float* __restrict__ ss) {
    size_t i4 = (size_t)blockIdx.x * 256 + threadIdx.x;
    int k4 = (int)(i4 % (BK_ / 4));
    int b = k4 / (K_ / 4);
    float scale = ss[b], shift = ss[B_ + b];
    float4* p = (float4*)out + i4;
    float4 v = *p;
    v.x = v.x * scale + shift;
    v.y = v.y * scale + shift;
    v.z = v.z * scale + shift;
    v.w = v.w * scale + shift;
    *p = v;
}

extern "C" void kernel_launch(void* const* d_in, const int* in_sizes, int n_in,
                              void* d_out, int out_size, void* d_ws, size_t ws_size,
                              hipStream_t stream) {
    const float* xr = (const float*)d_in[0];
    const float* xi = (const float*)d_in[1];
    const float* wr = (const float*)d_in[2];
    const float* wi = (const float*)d_in[3];
    const float* w_proj = (const float*)d_in[4];
    const float* gamma = (const float*)d_in[5];
    const float* beta = (const float*)d_in[6];
    float* out = (float*)d_out;

    _Float16* wp0 = (_Float16*)((char*)d_ws + WP0_OFF);
    _Float16* wp1 = (_Float16*)((char*)d_ws + WP1_OFF);
    _Float16* wp2 = (_Float16*)((char*)d_ws + WP2_OFF);
    float* wtail = (float*)((char*)d_ws + WTAIL_OFF);
    double* partials = (double*)((char*)d_ws + PART_OFF);
    float* ss = (float*)((char*)d_ws + SS_OFF);

    k_wt<<<81, 80, 0, stream>>>(w_proj, wp0, wp1, wp2, wtail);
    k_fused<<<NBLK, 512, 0, stream>>>(xr, xi, wr, wi, wp0, wp1, wp2, wtail, out, partials);
    k_bnstats<<<1, 256, 0, stream>>>(partials, gamma, beta, ss);
    k_bnapply<<<10000, 256, 0, stream>>>(out, ss);
}

// Round 18
// 206.056 us; speedup vs baseline: 3.8206x; 3.8206x over previous
//
#include <hip/hip_runtime.h>
#include <math.h>

#define N_ 16
#define C_ 4
#define F_ 257
#define T_ 1000
#define B_ 8
#define K_ 80
#define BK_ 640
#define TT_ 16
#define NT_ 63            // ceil(1000/16)
#define NBLK (N_ * NT_)   // 1008
#define NWAVE (NBLK * B_) // 8064 gemm waves

typedef _Float16 half4 __attribute__((ext_vector_type(4)));
typedef float f32x4 __attribute__((ext_vector_type(4)));

#define WSCALE   256.0f          // dodge f16 subnormals in w0
#define WUNSCALE 0.00390625f     // 2^-8

// d_ws byte offsets
#define WP0_OFF   0               // 80 frags * 64 lanes * 4 halves = 40960 B
#define WP1_OFF   (64 * 1024)
#define WP2_OFF   (128 * 1024)
#define WTAIL_OFF (192 * 1024)    // 80 f32
#define MAGT_OFF  (256 * 1024)    // 1008*16*8 f32 = 516 KB
#define PART_OFF  (1024 * 1024)   // 8064*2 doubles = 129 KB
#define SS_OFF    (PART_OFF + NWAVE * 2 * 8)
#define MAGF_OFF  (2 * 1024 * 1024)  // 1008*8*8*2*256 f32 = 126 MiB

// ---- pack w_proj into 16x16x16 B-fragment layout, 3-term f16 split --------
// frag blk = ch*10 + kt*2 + ksub. lane L, elem j:
//   B[f = ch*32 + ksub*16 + 4*(L/16) + j][k = kt*16 + L%16], scaled by 256.
__global__ __launch_bounds__(80) void k_wt(const float* __restrict__ wp,
                                           _Float16* __restrict__ wp0,
                                           _Float16* __restrict__ wp1,
                                           _Float16* __restrict__ wp2,
                                           float* __restrict__ wtail) {
    int blk = blockIdx.x;
    int tid = threadIdx.x;
    if (blk < 80) {
        if (tid < 64) {
            int ch = blk / 10, r = blk % 10, kt = r >> 1, ksub = r & 1;
            int k = kt * 16 + (tid & 15);
            int fb = ch * 32 + ksub * 16 + 4 * (tid >> 4);
#pragma unroll
            for (int j = 0; j < 4; ++j) {
                float w = wp[k * F_ + fb + j] * WSCALE;
                _Float16 w0 = (_Float16)w;
                float r1 = (w - (float)w0) * 2048.0f;
                _Float16 w1 = (_Float16)r1;
                float r2 = (r1 - (float)w1) * 2048.0f;
                _Float16 w2 = (_Float16)r2;
                size_t o = ((size_t)blk * 64 + tid) * 4 + j;
                wp0[o] = w0; wp1[o] = w1; wp2[o] = w2;
            }
        }
    } else {
        wtail[tid] = wp[tid * F_ + 256];   // f = 256 column, f32 (no scaling)
    }
}

// ---- kernel 1: beamform mag -> f32 A-fragment-ordered global buffer -------
// Block (n, tt), 512 threads, NO LDS, NO barriers. Thread = (f-row sfr, t_s).
// magF index (n,tt,b,ch,ks): frag of 256 floats; within frag: a_off.
// Wave stores per b are 256B contiguous (fully coalesced).
__global__ __launch_bounds__(512) void k_mag(
    const float* __restrict__ xr, const float* __restrict__ xi,
    const float* __restrict__ wr, const float* __restrict__ wi,
    float* __restrict__ magF, float* __restrict__ magT) {

    const int tid = threadIdx.x;
    const int bid = blockIdx.x;
    const int tt = bid % NT_;
    const int n  = bid / NT_;
    const int t0 = tt * TT_;

    const int sfr = tid >> 4;                 // f-row 0..31
    const int t_s = tid & 15;                 // t 0..15
    const int tg  = t0 + t_s;
    const bool tld = (tg < T_);
    const int a_ks = sfr >> 4;
    const int a_off = ((sfr & 15) >> 2) * 64 + t_s * 4 + (sfr & 3);

    const float* xrn = xr + (size_t)n * C_ * F_ * T_;
    const float* xin = xi + (size_t)n * C_ * F_ * T_;

    float pxr[C_], pxi[C_];
    if (tld) {
#pragma unroll
        for (int c = 0; c < C_; ++c) {
            pxr[c] = xrn[((size_t)c * F_ + sfr) * T_ + tg];
            pxi[c] = xin[((size_t)c * F_ + sfr) * T_ + tg];
        }
    }

    for (int ch = 0; ch < 8; ++ch) {
        const int f = ch * 32 + sfr;
        float m[B_];
        if (tld) {
            const float* wrp = wr + (size_t)f * B_ * C_;
            const float* wip = wi + (size_t)f * B_ * C_;
#pragma unroll
            for (int b = 0; b < B_; ++b) {
                float4 wrv = *(const float4*)(wrp + b * C_);
                float4 wiv = *(const float4*)(wip + b * C_);
                float br  = pxr[0] * wrv.x + pxr[1] * wrv.y + pxr[2] * wrv.z + pxr[3] * wrv.w
                          - pxi[0] * wiv.x - pxi[1] * wiv.y - pxi[2] * wiv.z - pxi[3] * wiv.w;
                float bi2 = pxi[0] * wrv.x + pxi[1] * wrv.y + pxi[2] * wrv.z + pxi[3] * wrv.w
                          + pxr[0] * wiv.x + pxr[1] * wiv.y + pxr[2] * wiv.z + pxr[3] * wiv.w;
                m[b] = sqrtf(br * br + bi2 * bi2 + 1e-5f);
            }
        } else {
#pragma unroll
            for (int b = 0; b < B_; ++b) m[b] = 0.f;
        }
        // prefetch next chunk
        if (ch < 7 && tld) {
            const int f2 = (ch + 1) * 32 + sfr;
#pragma unroll
            for (int c = 0; c < C_; ++c) {
                pxr[c] = xrn[((size_t)c * F_ + f2) * T_ + tg];
                pxi[c] = xin[((size_t)c * F_ + f2) * T_ + tg];
            }
        }
        // magF[(((bid*8 + b)*8 + ch)*2 + ks)*256 + a_off]; b-stride = 4096
        size_t base = ((((size_t)bid * B_) * 8 + ch) * 2 + a_ks) * 256 + a_off;
#pragma unroll
        for (int b = 0; b < B_; ++b)
            magF[base + (size_t)b * 4096] = m[b];
    }

    // tail f = 256 -> magT[(bid*16 + trow)*8 + b]
    if (tid < 128) {
        int trow = tid >> 3;
        int b = tid & 7;
        int t = t0 + trow;
        float v = 0.f;
        if (t < T_) {
            const float* wrp = wr + (size_t)(256 * B_ + b) * C_;
            const float* wip = wi + (size_t)(256 * B_ + b) * C_;
            float br = 0.f, bi2 = 0.f;
#pragma unroll
            for (int c = 0; c < C_; ++c) {
                float xrv = xrn[((size_t)c * F_ + 256) * T_ + t];
                float xiv = xin[((size_t)c * F_ + 256) * T_ + t];
                br  += xrv * wrp[c] - xiv * wip[c];
                bi2 += xiv * wrp[c] + xrv * wip[c];
            }
            v = sqrtf(br * br + bi2 * bi2 + 1e-5f);
        }
        magT[(size_t)bid * TT_ * B_ + trow * B_ + b] = v;
    }
}

// ---- kernel 2: pure MFMA GEMM, one wave per (n,tt,b). NO LDS, NO barriers.
__global__ __launch_bounds__(64) void k_gemm(
    const float* __restrict__ magF,
    const _Float16* __restrict__ wp0, const _Float16* __restrict__ wp1,
    const _Float16* __restrict__ wp2, const float* __restrict__ wtail,
    const float* __restrict__ magT,
    float* __restrict__ out, double* __restrict__ partials) {

    const int wid = blockIdx.x;               // (n*63+tt)*8 + b
    const int b   = wid & 7;
    const int nt  = wid >> 3;                 // n*63+tt
    const int tt  = nt % NT_;
    const int n   = nt / NT_;
    const int t0  = tt * TT_;
    const int lane = threadIdx.x;

    f32x4 accM[5], acc1[5], acc2[5];
#pragma unroll
    for (int kt = 0; kt < 5; ++kt) {
        accM[kt] = (f32x4)0.0f;
        acc1[kt] = (f32x4)0.0f;
        acc2[kt] = (f32x4)0.0f;
    }

    for (int ch = 0; ch < 8; ++ch) {
#pragma unroll
        for (int ks = 0; ks < 2; ++ks) {
            // A-frag: 4 consecutive f32 per lane (wave reads 1024B contiguous)
            f32x4 mv = *(const f32x4*)&magF[((((size_t)wid) * 8 + ch) * 2 + ks) * 256 + lane * 4];
            half4 a0, a1, a2;
#pragma unroll
            for (int j = 0; j < 4; ++j) {
                float v = mv[j];
                _Float16 h0 = (_Float16)v;
                float r1 = (v - (float)h0) * 2048.0f;
                _Float16 h1 = (_Float16)r1;
                float r2 = (r1 - (float)h1) * 2048.0f;
                a0[j] = h0; a1[j] = h1; a2[j] = (_Float16)r2;
            }
            const int fb = (ch * 10 + ks) * 64 + lane;   // +kt*2*64 per kt
#pragma unroll
            for (int kt = 0; kt < 5; ++kt) {
                half4 b0 = *(const half4*)&wp0[(size_t)(fb + kt * 128) * 4];
                accM[kt] = __builtin_amdgcn_mfma_f32_16x16x16f16(a0, b0, accM[kt], 0, 0, 0);
            }
#pragma unroll
            for (int kt = 0; kt < 5; ++kt) {
                half4 b1 = *(const half4*)&wp1[(size_t)(fb + kt * 128) * 4];
                acc1[kt] = __builtin_amdgcn_mfma_f32_16x16x16f16(a0, b1, acc1[kt], 0, 0, 0);
            }
#pragma unroll
            for (int kt = 0; kt < 5; ++kt) {
                half4 b0 = *(const half4*)&wp0[(size_t)(fb + kt * 128) * 4];
                acc1[kt] = __builtin_amdgcn_mfma_f32_16x16x16f16(a1, b0, acc1[kt], 0, 0, 0);
            }
#pragma unroll
            for (int kt = 0; kt < 5; ++kt) {
                half4 b2 = *(const half4*)&wp2[(size_t)(fb + kt * 128) * 4];
                acc2[kt] = __builtin_amdgcn_mfma_f32_16x16x16f16(a0, b2, acc2[kt], 0, 0, 0);
            }
#pragma unroll
            for (int kt = 0; kt < 5; ++kt) {
                half4 b1 = *(const half4*)&wp1[(size_t)(fb + kt * 128) * 4];
                acc2[kt] = __builtin_amdgcn_mfma_f32_16x16x16f16(a1, b1, acc2[kt], 0, 0, 0);
            }
#pragma unroll
            for (int kt = 0; kt < 5; ++kt) {
                half4 b0 = *(const half4*)&wp0[(size_t)(fb + kt * 128) * 4];
                acc2[kt] = __builtin_amdgcn_mfma_f32_16x16x16f16(a2, b0, acc2[kt], 0, 0, 0);
            }
        }
    }

    // ---- epilogue: combine (unscale) + f=256 tail, relu+log, store, BN ----
    const int col = lane & 15;
    const int g   = lane >> 4;
    float s1 = 0.f, s2 = 0.f;
#pragma unroll
    for (int kt = 0; kt < 5; ++kt) {
        f32x4 r = (accM[kt] + 4.8828125e-4f * acc1[kt]
                   + 2.384185791015625e-7f * acc2[kt]) * WUNSCALE;
#pragma unroll
        for (int reg = 0; reg < 4; ++reg) {
            int trow = 4 * g + reg;
            int t = t0 + trow;
            float sum = r[reg] + magT[(size_t)nt * TT_ * B_ + trow * B_ + b]
                                  * wtail[kt * 16 + col];
            if (t < T_) {
                float v = fmaxf(sum, 0.0f);
                v = __logf(v + 1e-5f);
                out[((size_t)n * T_ + t) * BK_ + b * K_ + kt * 16 + col] = v;
                s1 += v;
                s2 += v * v;
            }
        }
    }
    double d1 = (double)s1, d2 = (double)s2;
#pragma unroll
    for (int off = 32; off; off >>= 1) {
        d1 += __shfl_xor(d1, off);
        d2 += __shfl_xor(d2, off);
    }
    if (lane == 0) {
        partials[(size_t)wid * 2]     = d1;
        partials[(size_t)wid * 2 + 1] = d2;
    }
}

// ---------------- reduce partials -> per-channel scale/shift ----------------
__global__ __launch_bounds__(256) void k_bnstats(
    const double* __restrict__ partials,
    const float* __restrict__ gamma, const float* __restrict__ beta,
    float* __restrict__ ss) {
    const int b = threadIdx.x >> 5;
    const int i = threadIdx.x & 31;
    double s1 = 0.0, s2 = 0.0;
    for (int j = i; j < NBLK; j += 32) {
        s1 += partials[((size_t)j * 8 + b) * 2];
        s2 += partials[((size_t)j * 8 + b) * 2 + 1];
    }
#pragma unroll
    for (int off = 16; off; off >>= 1) {
        s1 += __shfl_down(s1, off);
        s2 += __shfl_down(s2, off);
    }
    if (i == 0) {
        const double cnt = (double)N_ * T_ * K_;
        double mean = s1 / cnt;
        double var = s2 / cnt - mean * mean;
        float scale = gamma[b] * (float)(1.0 / sqrt(var + 1e-5));
        float shift = beta[b] - (float)mean * scale;
        ss[b] = scale;
        ss[B_ + b] = shift;
    }
}

// ---------------- apply BN in place over d_out ----------------
__global__ __launch_bounds__(256) void k_bnapply(float* __restrict__ out,
                                                 const float* __restrict__ ss) {
    size_t i4 = (size_t)blockIdx.x * 256 + threadIdx.x;
    int k4 = (int)(i4 % (BK_ / 4));
    int b = k4 / (K_ / 4);
    float scale = ss[b], shift = ss[B_ + b];
    float4* p = (float4*)out + i4;
    float4 v = *p;
    v.x = v.x * scale + shift;
    v.y = v.y * scale + shift;
    v.z = v.z * scale + shift;
    v.w = v.w * scale + shift;
    *p = v;
}

extern "C" void kernel_launch(void* const* d_in, const int* in_sizes, int n_in,
                              void* d_out, int out_size, void* d_ws, size_t ws_size,
                              hipStream_t stream) {
    const float* xr = (const float*)d_in[0];
    const float* xi = (const float*)d_in[1];
    const float* wr = (const float*)d_in[2];
    const float* wi = (const float*)d_in[3];
    const float* w_proj = (const float*)d_in[4];
    const float* gamma = (const float*)d_in[5];
    const float* beta = (const float*)d_in[6];
    float* out = (float*)d_out;

    _Float16* wp0 = (_Float16*)((char*)d_ws + WP0_OFF);
    _Float16* wp1 = (_Float16*)((char*)d_ws + WP1_OFF);
    _Float16* wp2 = (_Float16*)((char*)d_ws + WP2_OFF);
    float* wtail = (float*)((char*)d_ws + WTAIL_OFF);
    float* magT = (float*)((char*)d_ws + MAGT_OFF);
    double* partials = (double*)((char*)d_ws + PART_OFF);
    float* ss = (float*)((char*)d_ws + SS_OFF);
    float* magF = (float*)((char*)d_ws + MAGF_OFF);

    k_wt<<<81, 80, 0, stream>>>(w_proj, wp0, wp1, wp2, wtail);
    k_mag<<<NBLK, 512, 0, stream>>>(xr, xi, wr, wi, magF, magT);
    k_gemm<<<NWAVE, 64, 0, stream>>>(magF, wp0, wp1, wp2, wtail, magT, out, partials);
    k_bnstats<<<1, 256, 0, stream>>>(partials, gamma, beta, ss);
    k_bnapply<<<10000, 256, 0, stream>>>(out, ss);
}

// Round 19
// 203.943 us; speedup vs baseline: 3.8602x; 1.0104x over previous
//
#include <hip/hip_runtime.h>
#include <math.h>

#define N_ 16
#define C_ 4
#define F_ 257
#define T_ 1000
#define B_ 8
#define K_ 80
#define BK_ 640
#define TT_ 16
#define NT_ 63            // ceil(1000/16)
#define NBLK (N_ * NT_)   // 1008
#define NWAVE (NBLK * B_) // 8064 gemm waves

typedef _Float16 half4 __attribute__((ext_vector_type(4)));
typedef float f32x4 __attribute__((ext_vector_type(4)));

#define WSCALE   256.0f          // dodge f16 subnormals in w0
#define WUNSCALE 0.00390625f     // 2^-8

// d_ws byte offsets
#define WP0_OFF   0               // 80 frags * 64 lanes * 4 halves = 40960 B
#define WP1_OFF   (64 * 1024)
#define WP2_OFF   (128 * 1024)
#define WTAIL_OFF (192 * 1024)    // 80 f32
#define MAGT_OFF  (256 * 1024)    // 1008*16*8 f32 = 516 KB
#define PART_OFF  (1024 * 1024)   // 8064*2 doubles = 129 KB
#define SS_OFF    (PART_OFF + NWAVE * 2 * 8)
#define MAGF_OFF  (2 * 1024 * 1024)  // 1008*8*8*2*256 f32 = 126 MiB

// ---- pack w_proj into 16x16x16 B-fragment layout, 3-term f16 split --------
// frag blk = ch*10 + kt*2 + ksub. lane L, elem j:
//   B[f = ch*32 + ksub*16 + 4*(L/16) + j][k = kt*16 + L%16], scaled by 256.
__global__ __launch_bounds__(80) void k_wt(const float* __restrict__ wp,
                                           _Float16* __restrict__ wp0,
                                           _Float16* __restrict__ wp1,
                                           _Float16* __restrict__ wp2,
                                           float* __restrict__ wtail) {
    int blk = blockIdx.x;
    int tid = threadIdx.x;
    if (blk < 80) {
        if (tid < 64) {
            int ch = blk / 10, r = blk % 10, kt = r >> 1, ksub = r & 1;
            int k = kt * 16 + (tid & 15);
            int fb = ch * 32 + ksub * 16 + 4 * (tid >> 4);
#pragma unroll
            for (int j = 0; j < 4; ++j) {
                float w = wp[k * F_ + fb + j] * WSCALE;
                _Float16 w0 = (_Float16)w;
                float r1 = (w - (float)w0) * 2048.0f;
                _Float16 w1 = (_Float16)r1;
                float r2 = (r1 - (float)w1) * 2048.0f;
                _Float16 w2 = (_Float16)r2;
                size_t o = ((size_t)blk * 64 + tid) * 4 + j;
                wp0[o] = w0; wp1[o] = w1; wp2[o] = w2;
            }
        }
    } else {
        wtail[tid] = wp[tid * F_ + 256];   // f = 256 column, f32 (no scaling)
    }
}

// ---- kernel 1: beamform mag -> f32 A-fragment buffer, t-major-in-j layout --
// frag elem order: a_off = g*64 + j*16 + t   (g = f-quad, j = f-elem, t 0..15)
// Thread: csub=tid>>7 (chunk-sub 0..3), sfr=(tid>>2)&31 (f-row), tq=tid&3.
// Per outer it (2): ch = it*4+csub. float4 x loads over t; float4 mag stores.
// Wave stores cover contiguous 1KB -> fully coalesced. NO LDS, NO barriers.
__global__ __launch_bounds__(512) void k_mag(
    const float* __restrict__ xr, const float* __restrict__ xi,
    const float* __restrict__ wr, const float* __restrict__ wi,
    float* __restrict__ magF, float* __restrict__ magT) {

    const int tid = threadIdx.x;
    const int bid = blockIdx.x;
    const int tt = bid % NT_;
    const int n  = bid / NT_;
    const int t0 = tt * TT_;

    const int csub = tid >> 7;                // chunk-sub 0..3
    const int sfr  = (tid >> 2) & 31;         // f-row 0..31
    const int tq   = tid & 3;                 // t-quad 0..3
    const int tb   = t0 + tq * 4;
    const bool tld = (tb + 4 <= T_);
    const int a_ks = sfr >> 4;
    const int g    = (sfr >> 2) & 3;
    const int j    = sfr & 3;
    const int a_off = g * 64 + j * 16 + tq * 4;

    const float* xrn = xr + (size_t)n * C_ * F_ * T_;
    const float* xin = xi + (size_t)n * C_ * F_ * T_;

    // prefetch x for it=0 (ch = csub)
    float4 pxr[C_], pxi[C_];
    if (tld) {
        const int f = csub * 32 + sfr;
#pragma unroll
        for (int c = 0; c < C_; ++c) {
            pxr[c] = *(const float4*)(xrn + ((size_t)c * F_ + f) * T_ + tb);
            pxi[c] = *(const float4*)(xin + ((size_t)c * F_ + f) * T_ + tb);
        }
    }

#pragma unroll
    for (int it = 0; it < 2; ++it) {
        const int ch = it * 4 + csub;
        const int f  = ch * 32 + sfr;
        float m[4][B_];   // [t][b]
        if (tld) {
            float xrv[C_][4], xiv[C_][4];
#pragma unroll
            for (int c = 0; c < C_; ++c) {
                xrv[c][0] = pxr[c].x; xrv[c][1] = pxr[c].y;
                xrv[c][2] = pxr[c].z; xrv[c][3] = pxr[c].w;
                xiv[c][0] = pxi[c].x; xiv[c][1] = pxi[c].y;
                xiv[c][2] = pxi[c].z; xiv[c][3] = pxi[c].w;
            }
            const float* wrp = wr + (size_t)f * B_ * C_;
            const float* wip = wi + (size_t)f * B_ * C_;
#pragma unroll
            for (int b = 0; b < B_; ++b) {
                float4 wrv = *(const float4*)(wrp + b * C_);
                float4 wiv = *(const float4*)(wip + b * C_);
                float wrc[4] = {wrv.x, wrv.y, wrv.z, wrv.w};
                float wic[4] = {wiv.x, wiv.y, wiv.z, wiv.w};
#pragma unroll
                for (int i = 0; i < 4; ++i) {
                    float br = 0.f, bi2 = 0.f;
#pragma unroll
                    for (int c = 0; c < C_; ++c) {
                        br  += xrv[c][i] * wrc[c] - xiv[c][i] * wic[c];
                        bi2 += xiv[c][i] * wrc[c] + xrv[c][i] * wic[c];
                    }
                    m[i][b] = sqrtf(br * br + bi2 * bi2 + 1e-5f);
                }
            }
        } else {
#pragma unroll
            for (int i = 0; i < 4; ++i)
#pragma unroll
                for (int b = 0; b < B_; ++b) m[i][b] = 0.f;
        }
        // prefetch x for it=1
        if (it == 0 && tld) {
            const int f2 = (4 + csub) * 32 + sfr;
#pragma unroll
            for (int c = 0; c < C_; ++c) {
                pxr[c] = *(const float4*)(xrn + ((size_t)c * F_ + f2) * T_ + tb);
                pxi[c] = *(const float4*)(xin + ((size_t)c * F_ + f2) * T_ + tb);
            }
        }
        // stores: one float4 per b
        size_t base = ((((size_t)bid * B_) * 8 + ch) * 2 + a_ks) * 256 + a_off;
#pragma unroll
        for (int b = 0; b < B_; ++b)
            *(float4*)&magF[base + (size_t)b * 4096] =
                make_float4(m[0][b], m[1][b], m[2][b], m[3][b]);
    }

    // tail f = 256 -> magT[(bid*16 + trow)*8 + b]
    if (tid < 128) {
        int trow = tid >> 3;
        int b = tid & 7;
        int t = t0 + trow;
        float v = 0.f;
        if (t < T_) {
            const float* wrp = wr + (size_t)(256 * B_ + b) * C_;
            const float* wip = wi + (size_t)(256 * B_ + b) * C_;
            float br = 0.f, bi2 = 0.f;
#pragma unroll
            for (int c = 0; c < C_; ++c) {
                float xrv = xrn[((size_t)c * F_ + 256) * T_ + t];
                float xiv = xin[((size_t)c * F_ + 256) * T_ + t];
                br  += xrv * wrp[c] - xiv * wip[c];
                bi2 += xiv * wrp[c] + xrv * wip[c];
            }
            v = sqrtf(br * br + bi2 * bi2 + 1e-5f);
        }
        magT[(size_t)bid * TT_ * B_ + trow * B_ + b] = v;
    }
}

// ---- kernel 2: pure MFMA GEMM; 256 threads = 4 waves, wave = (nt,b). ------
// NO LDS, NO barriers. A from magF (t-major layout: 4 coalesced scalar loads
// per frag), B-frags from global (L1/L2-resident, 15KB working set/chunk).
__global__ __launch_bounds__(256) void k_gemm(
    const float* __restrict__ magF,
    const _Float16* __restrict__ wp0, const _Float16* __restrict__ wp1,
    const _Float16* __restrict__ wp2, const float* __restrict__ wtail,
    const float* __restrict__ magT,
    float* __restrict__ out, double* __restrict__ partials) {

    const int wid = blockIdx.x * 4 + (threadIdx.x >> 6);   // (n*63+tt)*8 + b
    const int b   = wid & 7;
    const int nt  = wid >> 3;
    const int tt  = nt % NT_;
    const int n   = nt / NT_;
    const int t0  = tt * TT_;
    const int lane = threadIdx.x & 63;

    const int a_t = lane & 15;
    const int a_g = lane >> 4;

    f32x4 accM[5], acc1[5], acc2[5];
#pragma unroll
    for (int kt = 0; kt < 5; ++kt) {
        accM[kt] = (f32x4)0.0f;
        acc1[kt] = (f32x4)0.0f;
        acc2[kt] = (f32x4)0.0f;
    }

    for (int ch = 0; ch < 8; ++ch) {
#pragma unroll
        for (int ks = 0; ks < 2; ++ks) {
            const float* frag = &magF[((((size_t)wid) * 8 + ch) * 2 + ks) * 256];
            half4 a0, a1, a2;
#pragma unroll
            for (int j = 0; j < 4; ++j) {
                float v = frag[a_g * 64 + j * 16 + a_t];
                _Float16 h0 = (_Float16)v;
                float r1 = (v - (float)h0) * 2048.0f;
                _Float16 h1 = (_Float16)r1;
                float r2 = (r1 - (float)h1) * 2048.0f;
                a0[j] = h0; a1[j] = h1; a2[j] = (_Float16)r2;
            }
            const int fb = (ch * 10 + ks) * 64 + lane;   // +kt*128 per kt
#pragma unroll
            for (int kt = 0; kt < 5; ++kt) {
                half4 b0 = *(const half4*)&wp0[(size_t)(fb + kt * 128) * 4];
                accM[kt] = __builtin_amdgcn_mfma_f32_16x16x16f16(a0, b0, accM[kt], 0, 0, 0);
            }
#pragma unroll
            for (int kt = 0; kt < 5; ++kt) {
                half4 b1 = *(const half4*)&wp1[(size_t)(fb + kt * 128) * 4];
                acc1[kt] = __builtin_amdgcn_mfma_f32_16x16x16f16(a0, b1, acc1[kt], 0, 0, 0);
            }
#pragma unroll
            for (int kt = 0; kt < 5; ++kt) {
                half4 b0 = *(const half4*)&wp0[(size_t)(fb + kt * 128) * 4];
                acc1[kt] = __builtin_amdgcn_mfma_f32_16x16x16f16(a1, b0, acc1[kt], 0, 0, 0);
            }
#pragma unroll
            for (int kt = 0; kt < 5; ++kt) {
                half4 b2 = *(const half4*)&wp2[(size_t)(fb + kt * 128) * 4];
                acc2[kt] = __builtin_amdgcn_mfma_f32_16x16x16f16(a0, b2, acc2[kt], 0, 0, 0);
            }
#pragma unroll
            for (int kt = 0; kt < 5; ++kt) {
                half4 b1 = *(const half4*)&wp1[(size_t)(fb + kt * 128) * 4];
                acc2[kt] = __builtin_amdgcn_mfma_f32_16x16x16f16(a1, b1, acc2[kt], 0, 0, 0);
            }
#pragma unroll
            for (int kt = 0; kt < 5; ++kt) {
                half4 b0 = *(const half4*)&wp0[(size_t)(fb + kt * 128) * 4];
                acc2[kt] = __builtin_amdgcn_mfma_f32_16x16x16f16(a2, b0, acc2[kt], 0, 0, 0);
            }
        }
    }

    // ---- epilogue: combine (unscale) + f=256 tail, relu+log, store, BN ----
    const int col = lane & 15;
    const int g   = lane >> 4;
    float s1 = 0.f, s2 = 0.f;
#pragma unroll
    for (int kt = 0; kt < 5; ++kt) {
        f32x4 r = (accM[kt] + 4.8828125e-4f * acc1[kt]
                   + 2.384185791015625e-7f * acc2[kt]) * WUNSCALE;
#pragma unroll
        for (int reg = 0; reg < 4; ++reg) {
            int trow = 4 * g + reg;
            int t = t0 + trow;
            float sum = r[reg] + magT[(size_t)nt * TT_ * B_ + trow * B_ + b]
                                  * wtail[kt * 16 + col];
            if (t < T_) {
                float v = fmaxf(sum, 0.0f);
                v = __logf(v + 1e-5f);
                out[((size_t)n * T_ + t) * BK_ + b * K_ + kt * 16 + col] = v;
                s1 += v;
                s2 += v * v;
            }
        }
    }
    double d1 = (double)s1, d2 = (double)s2;
#pragma unroll
    for (int off = 32; off; off >>= 1) {
        d1 += __shfl_xor(d1, off);
        d2 += __shfl_xor(d2, off);
    }
    if (lane == 0) {
        partials[(size_t)wid * 2]     = d1;
        partials[(size_t)wid * 2 + 1] = d2;
    }
}

// ---------------- reduce partials -> per-channel scale/shift ----------------
__global__ __launch_bounds__(256) void k_bnstats(
    const double* __restrict__ partials,
    const float* __restrict__ gamma, const float* __restrict__ beta,
    float* __restrict__ ss) {
    const int b = threadIdx.x >> 5;
    const int i = threadIdx.x & 31;
    double s1 = 0.0, s2 = 0.0;
    for (int j = i; j < NBLK; j += 32) {
        s1 += partials[((size_t)j * 8 + b) * 2];
        s2 += partials[((size_t)j * 8 + b) * 2 + 1];
    }
#pragma unroll
    for (int off = 16; off; off >>= 1) {
        s1 += __shfl_down(s1, off);
        s2 += __shfl_down(s2, off);
    }
    if (i == 0) {
        const double cnt = (double)N_ * T_ * K_;
        double mean = s1 / cnt;
        double var = s2 / cnt - mean * mean;
        float scale = gamma[b] * (float)(1.0 / sqrt(var + 1e-5));
        float shift = beta[b] - (float)mean * scale;
        ss[b] = scale;
        ss[B_ + b] = shift;
    }
}

// ---------------- apply BN in place over d_out ----------------
__global__ __launch_bounds__(256) void k_bnapply(float* __restrict__ out,
                                                 const float* __restrict__ ss) {
    size_t i4 = (size_t)blockIdx.x * 256 + threadIdx.x;
    int k4 = (int)(i4 % (BK_ / 4));
    int b = k4 / (K_ / 4);
    float scale = ss[b], shift = ss[B_ + b];
    float4* p = (float4*)out + i4;
    float4 v = *p;
    v.x = v.x * scale + shift;
    v.y = v.y * scale + shift;
    v.z = v.z * scale + shift;
    v.w = v.w * scale + shift;
    *p = v;
}

extern "C" void kernel_launch(void* const* d_in, const int* in_sizes, int n_in,
                              void* d_out, int out_size, void* d_ws, size_t ws_size,
                              hipStream_t stream) {
    const float* xr = (const float*)d_in[0];
    const float* xi = (const float*)d_in[1];
    const float* wr = (const float*)d_in[2];
    const float* wi = (const float*)d_in[3];
    const float* w_proj = (const float*)d_in[4];
    const float* gamma = (const float*)d_in[5];
    const float* beta = (const float*)d_in[6];
    float* out = (float*)d_out;

    _Float16* wp0 = (_Float16*)((char*)d_ws + WP0_OFF);
    _Float16* wp1 = (_Float16*)((char*)d_ws + WP1_OFF);
    _Float16* wp2 = (_Float16*)((char*)d_ws + WP2_OFF);
    float* wtail = (float*)((char*)d_ws + WTAIL_OFF);
    float* magT = (float*)((char*)d_ws + MAGT_OFF);
    double* partials = (double*)((char*)d_ws + PART_OFF);
    float* ss = (float*)((char*)d_ws + SS_OFF);
    float* magF = (float*)((char*)d_ws + MAGF_OFF);

    k_wt<<<81, 80, 0, stream>>>(w_proj, wp0, wp1, wp2, wtail);
    k_mag<<<NBLK, 512, 0, stream>>>(xr, xi, wr, wi, magF, magT);
    k_gemm<<<NWAVE / 4, 256, 0, stream>>>(magF, wp0, wp1, wp2, wtail, magT, out, partials);
    k_bnstats<<<1, 256, 0, stream>>>(partials, gamma, beta, ss);
    k_bnapply<<<10000, 256, 0, stream>>>(out, ss);
}